// Round 8
// baseline (63.585 us; speedup 1.0000x reference)
//
#include <hip/hip_runtime.h>
#include <hip/hip_bf16.h>

#define B_ 8
#define C_ 64
#define O_ 64
#define H_ 128
#define W_ 128
#define HW_ (H_ * W_)

#define WFRAG_US 36864                        // 73728 B of weight fragments
#define ZROW (B_ * H_ * 130)                  // zero-row index in xT
#define XT_US ((size_t)(ZROW + 130) * 64)     // xT elements (incl. zero row)
#define WS_NEEDED (73728 + XT_US * 2)

typedef __attribute__((ext_vector_type(8))) short bf16x8;
typedef __attribute__((ext_vector_type(4))) float f32x4;

__device__ __forceinline__ unsigned short f2bf(float v) {
    unsigned u = __float_as_uint(v);
    return (unsigned short)((u + 0x7FFFu + ((u >> 16) & 1u)) >> 16);
}
__device__ __forceinline__ int swz(int col) {   // 16B slot selector (fallback)
    return ((col ^ (col >> 3)) & 7) << 4;
}
__device__ __forceinline__ int clampi(int v, int lo, int hi) {
    return v < lo ? lo : (v > hi ? hi : v);
}

// ---- weight prep: wfrag flat = (((t*2+ks)*4+fi)*64 + lane)*8 + j ----
// o = fi*16 + (lane&15), c = ks*32 + ((lane>>4)&3)*8 + j  (MFMA B-frag order)
__global__ void prep_weights(const float* __restrict__ weight,
                             unsigned short* __restrict__ wfrag) {
    int idx = blockIdx.x * 256 + threadIdx.x;
    if (idx >= 9 * 4096) return;
    int j  = idx & 7;
    int l  = (idx >> 3) & 63;
    int fi = (idx >> 9) & 3;
    int ks = (idx >> 11) & 1;
    int t  = idx >> 12;
    int o  = fi * 16 + (l & 15);
    int c  = ks * 32 + ((l >> 4) & 3) * 8 + j;
    wfrag[idx] = f2bf(weight[(o * C_ + c) * 9 + t]);
}

// ---- x transpose: xT[(b*128+h)*130 + (w+1)][c] = bf16(x[b][c][h][w]) ----
// cols 0 and 129 zeroed (w halo); row ZROW zeroed (h halo).
__global__ __launch_bounds__(256)
void prep_x(const float* __restrict__ x, unsigned short* __restrict__ xT) {
    __shared__ unsigned short tile[128][68];   // [w][c], stride 136B
    const int tid = threadIdx.x;
    const int blk = blockIdx.x;                // 1024 = 8 b x 128 h
    const int b = blk >> 7, h = blk & 127;
    const int w4 = tid & 31;                   // float4 slot along w
    const int cg = tid >> 5;                   // channel group 0..7

    float4 v[8];
    #pragma unroll
    for (int k = 0; k < 8; ++k) {
        int c = cg * 8 + k;
        v[k] = *(const float4*)&x[((b * C_ + c) * H_ + h) * W_ + w4 * 4];
    }
    #pragma unroll
    for (int j = 0; j < 4; ++j) {
        bf16x8 pk;
        #pragma unroll
        for (int k = 0; k < 8; ++k)
            pk[k] = (short)f2bf(((const float*)&v[k])[j]);
        *(bf16x8*)&tile[w4 * 4 + j][cg * 8] = pk;
    }
    __syncthreads();
    #pragma unroll
    for (int p = 0; p < 4; ++p) {
        int idx  = p * 256 + tid;
        int wrow = idx >> 3, ch = idx & 7;
        bf16x8 val = *(const bf16x8*)&tile[wrow][ch * 8];
        *(bf16x8*)&xT[(size_t)((b * H_ + h) * 130 + wrow + 1) * 64 + ch * 8] = val;
    }
    if (tid < 16) {                            // zero w-halo cols 0 and 129
        bf16x8 z = {};
        int col = (tid < 8) ? 0 : 129;
        int ch  = tid & 7;
        *(bf16x8*)&xT[(size_t)((b * H_ + h) * 130 + col) * 64 + ch * 8] = z;
    }
    if (blk == 0) {                            // zero h-halo row
        bf16x8 z = {};
        for (int i = tid; i < 1040; i += 256)
            *(bf16x8*)&xT[(size_t)ZROW * 64 + i * 8] = z;
    }
}

// ---- main: no x staging. Block = (b = blk&7 -> XCD, 2-row x 64-col tile).
// 4 waves: wave = (hr = wv>>1, oh = wv&1): 1 output row x 32 o x 64 px.
// A-fragments load straight from xT (L2-resident), 16B/lane coalesced.
__global__ __launch_bounds__(256, 4)
void depthconv_xt(const float* __restrict__ depth,
                  const unsigned short* __restrict__ wfrag,
                  const unsigned short* __restrict__ xT,
                  const float* __restrict__ bias,
                  float* __restrict__ out) {
    __shared__ float sim[9][2][64];            // 4608 B
    __shared__ float dt[4][68];                // 1088 B

    const int tid  = threadIdx.x;
    const int blk  = blockIdx.x;               // 1024
    const int b    = blk & 7;                  // batch -> XCD affinity
    const int tile = blk >> 3;                 // 0..127
    const int h0   = (tile >> 1) * 2;
    const int w0   = (tile & 1) * 64;

    // depth tile: rows h0-1..h0+2, cols w0-1..w0+64
    for (int i = tid; i < 264; i += 256) {
        int r = i / 66, col = i - r * 66;
        int gh = h0 - 1 + r, gw = w0 - 1 + col;
        bool ok = ((unsigned)gh < (unsigned)H_) && ((unsigned)gw < (unsigned)W_);
        float v = depth[(b * H_ + clampi(gh, 0, H_ - 1)) * W_ + clampi(gw, 0, W_ - 1)];
        dt[r][col] = ok ? v : 0.f;
    }
    __syncthreads();
    for (int i = tid; i < 1152; i += 256) {
        int t = i >> 7, sr = (i >> 6) & 1, px = i & 63;
        int kh = t / 3, kw = t - kh * 3;
        sim[t][sr][px] = expf(-fabsf(dt[sr + kh][px + kw] - dt[sr + 1][px + 1]));
    }
    __syncthreads();

    const int lane = tid & 63;
    const int wv   = tid >> 6;
    const int hr   = wv >> 1;
    const int oh   = wv & 1;
    const int g    = lane >> 4;
    const int ln   = lane & 15;

    float acc[4][2][4];
    #pragma unroll
    for (int of = 0; of < 2; ++of) {
        float bv = bias[(oh * 2 + of) * 16 + ln];
        #pragma unroll
        for (int pf = 0; pf < 4; ++pf)
            #pragma unroll
            for (int r = 0; r < 4; ++r)
                acc[pf][of][r] = bv;
    }

    #pragma unroll 1
    for (int kh = 0; kh < 3; ++kh) {
        int gh = h0 + hr + kh - 1;
        unsigned rowe = ((unsigned)gh < (unsigned)H_)
                      ? (unsigned)((b * H_ + gh) * 130) : (unsigned)ZROW;
        unsigned basee = (rowe + w0 + ln) * 64 + g * 8;   // + (pf*16+kw)*64
        #pragma unroll
        for (int kw = 0; kw < 3; ++kw) {
            const int t = kh * 3 + kw;
            bf16x8 bfr[2][2];
            #pragma unroll
            for (int ks = 0; ks < 2; ++ks)
                #pragma unroll
                for (int of = 0; of < 2; ++of) {
                    int fi = oh * 2 + of;
                    bfr[ks][of] = *(const bf16x8*)(
                        wfrag + (((t * 2 + ks) * 4 + fi) * 64 + lane) * 8);
                }
            #pragma unroll
            for (int pf = 0; pf < 4; ++pf) {
                unsigned off = basee + (pf * 16 + kw) * 64;
                bf16x8 af0 = *(const bf16x8*)(xT + off);
                bf16x8 af1 = *(const bf16x8*)(xT + off + 32);

                f32x4 prt[2] = {};
                #pragma unroll
                for (int of = 0; of < 2; ++of)
                    prt[of] = __builtin_amdgcn_mfma_f32_16x16x32_bf16(
                        af0, bfr[0][of], prt[of], 0, 0, 0);
                #pragma unroll
                for (int of = 0; of < 2; ++of)
                    prt[of] = __builtin_amdgcn_mfma_f32_16x16x32_bf16(
                        af1, bfr[1][of], prt[of], 0, 0, 0);

                f32x4 sv = *(const f32x4*)&sim[t][hr][pf * 16 + g * 4];
                #pragma unroll
                for (int of = 0; of < 2; ++of)
                    #pragma unroll
                    for (int r = 0; r < 4; ++r)
                        acc[pf][of][r] = fmaf(sv[r], prt[of][r], acc[pf][of][r]);
            }
        }
    }

    // stores: proven-clean pattern (4 g-lanes form 64B chunks, full rows)
    const int h = h0 + hr;
    #pragma unroll
    for (int of = 0; of < 2; ++of) {
        int o = (oh * 2 + of) * 16 + ln;
        float* dst = out + (((size_t)(b * O_ + o) * H_ + h) * W_) + w0;
        #pragma unroll
        for (int pf = 0; pf < 4; ++pf) {
            f32x4 v = { acc[pf][of][0], acc[pf][of][1],
                        acc[pf][of][2], acc[pf][of][3] };
            *(f32x4*)(dst + pf * 16 + g * 4) = v;
        }
    }
}

// ================= fallback: round-5 kernel (36.6us), used if ws too small ==
__global__ __launch_bounds__(256, 2)
void depthconv_fb(const float* __restrict__ x,
                  const float* __restrict__ depth,
                  const unsigned short* __restrict__ wfrag,
                  const float* __restrict__ bias,
                  float* __restrict__ out) {
    __shared__ __align__(16) unsigned char xs[396 * 128];
    __shared__ __align__(16) float sim[9][4][64];
    __shared__ __align__(16) float dt[6][68];

    const int tid = threadIdx.x;
    const int blk = blockIdx.x;
    const int b   = blk >> 6;
    const int rem = blk & 63;
    const int h0  = (rem >> 1) * 4;
    const int w0  = (rem & 1) * 64;

    for (int i = tid; i < 396; i += 256) {
        int r = i / 66, col = i - r * 66;
        int gh = h0 - 1 + r, gw = w0 - 1 + col;
        bool ok = ((unsigned)gh < (unsigned)H_) && ((unsigned)gw < (unsigned)W_);
        float v = depth[(b * H_ + clampi(gh, 0, H_ - 1)) * W_ + clampi(gw, 0, W_ - 1)];
        dt[r][col] = ok ? v : 0.f;
    }
    __syncthreads();

    const int q  = tid & 15;
    const int pc = tid >> 4;
    float4 xa[12], xb[12];
    #pragma unroll
    for (int k = 0; k < 12; ++k) {
        int r = k >> 1, pair = pc + 16 * (k & 1);
        int ghc = clampi(h0 - 1 + r, 0, H_ - 1);
        const float* p = &x[((b * C_ + 2 * pair) * H_ + ghc) * W_ + w0 + q * 4];
        xa[k] = *(const float4*)p;
        xb[k] = *(const float4*)(p + HW_);
    }
    float hl0[2], hl1[2]; int hside[2], hpair[2], hr_[2]; bool hact[2];
    #pragma unroll
    for (int k = 0; k < 2; ++k) {
        int i = tid + 256 * k; hact[k] = false;
        if (i < 384) {
            int side = i & 1, pair = (i >> 1) & 31, r = i >> 6;
            hside[k] = side; hpair[k] = pair; hr_[k] = r; hact[k] = true;
            int gh = h0 - 1 + r, gw = side ? (w0 + 64) : (w0 - 1);
            bool ok = ((unsigned)gh < (unsigned)H_) && ((unsigned)gw < (unsigned)W_);
            const float* p = &x[((b * C_ + 2 * pair) * H_ + clampi(gh, 0, H_ - 1)) * W_
                                + clampi(gw, 0, W_ - 1)];
            float v0 = p[0], v1 = p[HW_];
            hl0[k] = ok ? v0 : 0.f; hl1[k] = ok ? v1 : 0.f;
        }
    }
    {
        int sr = (tid >> 6) & 3, px = tid & 63;
        float dc = dt[sr + 1][px + 1];
        #pragma unroll
        for (int t = 0; t < 9; ++t) {
            const int kh = t / 3, kw = t % 3;
            sim[t][sr][px] = expf(-fabsf(dt[sr + kh][px + kw] - dc));
        }
    }
    #pragma unroll
    for (int k = 0; k < 12; ++k) {
        int r = k >> 1, pair = pc + 16 * (k & 1);
        bool okh = (unsigned)(h0 - 1 + r) < (unsigned)H_;
        float va[4] = {xa[k].x, xa[k].y, xa[k].z, xa[k].w};
        float vb[4] = {xb[k].x, xb[k].y, xb[k].z, xb[k].w};
        #pragma unroll
        for (int m = 0; m < 4; ++m) {
            int col = 1 + q * 4 + m;
            float2 pr; pr.x = okh ? va[m] : 0.f; pr.y = okh ? vb[m] : 0.f;
            __hip_bfloat162 bv = __float22bfloat162_rn(pr);
            *(__hip_bfloat162*)(xs + (r * 66 + col) * 128 + ((4 * pair) ^ swz(col))) = bv;
        }
    }
    #pragma unroll
    for (int k = 0; k < 2; ++k) {
        if (hact[k]) {
            int col = hside[k] ? 65 : 0;
            float2 pr; pr.x = hl0[k]; pr.y = hl1[k];
            __hip_bfloat162 bv = __float22bfloat162_rn(pr);
            *(__hip_bfloat162*)(xs + (hr_[k] * 66 + col) * 128 + ((4 * hpair[k]) ^ swz(col))) = bv;
        }
    }
    __syncthreads();

    const int lane = tid & 63, hr = tid >> 6, g = lane >> 4, ln = lane & 15;
    float acc[4][4][4];
    #pragma unroll
    for (int of = 0; of < 4; ++of) {
        float bv = bias[of * 16 + ln];
        #pragma unroll
        for (int pf = 0; pf < 4; ++pf)
            #pragma unroll
            for (int r = 0; r < 4; ++r) acc[pf][of][r] = bv;
    }
    #pragma unroll 1
    for (int kh = 0; kh < 3; ++kh) {
        #pragma unroll
        for (int kw = 0; kw < 3; ++kw) {
            const int t = kh * 3 + kw;
            bf16x8 bfr[2][4];
            #pragma unroll
            for (int ks = 0; ks < 2; ++ks)
                #pragma unroll
                for (int of = 0; of < 4; ++of)
                    bfr[ks][of] = *(const bf16x8*)(
                        wfrag + (((t * 2 + ks) * 4 + of) * 64 + lane) * 8);
            #pragma unroll
            for (int pf = 0; pf < 4; ++pf) {
                int col = pf * 16 + ln + kw;
                const unsigned char* rowp = xs + ((hr + kh) * 66 + col) * 128;
                bf16x8 af0 = *(const bf16x8*)(rowp + ((16 * g) ^ swz(col)));
                bf16x8 af1 = *(const bf16x8*)(rowp + ((64 + 16 * g) ^ swz(col)));
                f32x4 prt[4] = {};
                #pragma unroll
                for (int of = 0; of < 4; ++of)
                    prt[of] = __builtin_amdgcn_mfma_f32_16x16x32_bf16(
                        af0, bfr[0][of], prt[of], 0, 0, 0);
                #pragma unroll
                for (int of = 0; of < 4; ++of)
                    prt[of] = __builtin_amdgcn_mfma_f32_16x16x32_bf16(
                        af1, bfr[1][of], prt[of], 0, 0, 0);
                f32x4 sv = *(const f32x4*)&sim[t][hr][pf * 16 + g * 4];
                #pragma unroll
                for (int of = 0; of < 4; ++of)
                    #pragma unroll
                    for (int r = 0; r < 4; ++r)
                        acc[pf][of][r] = fmaf(sv[r], prt[of][r], acc[pf][of][r]);
            }
        }
    }
    const int h = h0 + hr;
    #pragma unroll
    for (int of = 0; of < 4; ++of) {
        int o = of * 16 + ln;
        float* dst = out + (((size_t)(b * O_ + o) * H_ + h) * W_) + w0;
        #pragma unroll
        for (int pf = 0; pf < 4; ++pf) {
            f32x4 v = { acc[pf][of][0], acc[pf][of][1],
                        acc[pf][of][2], acc[pf][of][3] };
            *(f32x4*)(dst + pf * 16 + g * 4) = v;
        }
    }
}

extern "C" void kernel_launch(void* const* d_in, const int* in_sizes, int n_in,
                              void* d_out, int out_size, void* d_ws, size_t ws_size,
                              hipStream_t stream) {
    const float* x      = (const float*)d_in[0];
    const float* depth  = (const float*)d_in[1];
    const float* weight = (const float*)d_in[2];
    const float* bias   = (const float*)d_in[3];
    float* out          = (float*)d_out;
    unsigned short* wfrag = (unsigned short*)d_ws;

    prep_weights<<<dim3(144), dim3(256), 0, stream>>>(weight, wfrag);
    if (ws_size >= WS_NEEDED) {
        unsigned short* xT = wfrag + WFRAG_US;
        prep_x<<<dim3(1024), dim3(256), 0, stream>>>(x, xT);
        depthconv_xt<<<dim3(1024), dim3(256), 0, stream>>>(
            depth, wfrag, xT, bias, out);
    } else {
        depthconv_fb<<<dim3(512), dim3(256), 0, stream>>>(
            x, depth, wfrag, bias, out);
    }
}

// Round 9
// 44.010 us; speedup vs baseline: 1.4448x; 1.4448x over previous
//
#include <hip/hip_runtime.h>
#include <hip/hip_bf16.h>

#define B_ 8
#define C_ 64
#define O_ 64
#define H_ 128
#define W_ 128
#define HW_ (H_ * W_)

#define WFRAG_US 36864                        // 73728 B of weight fragments
#define ZROW (B_ * H_ * 130)                  // zero-row index in xT
#define XT_US ((size_t)(ZROW + 130) * 64)     // xT elements (incl. zero row)
#define WS_NEEDED (73728 + XT_US * 2)

typedef __attribute__((ext_vector_type(8))) short bf16x8;
typedef __attribute__((ext_vector_type(4))) float f32x4;

#define GLOAD_LDS16(g, l)                                                     \
    __builtin_amdgcn_global_load_lds(                                         \
        (const __attribute__((address_space(1))) void*)(g),                   \
        (__attribute__((address_space(3))) void*)(l), 16, 0, 0)

__device__ __forceinline__ unsigned short f2bf(float v) {
    unsigned u = __float_as_uint(v);
    return (unsigned short)((u + 0x7FFFu + ((u >> 16) & 1u)) >> 16);
}
__device__ __forceinline__ int swz(int col) {   // 16B slot selector
    return ((col ^ (col >> 3)) & 7) << 4;
}
__device__ __forceinline__ int clampi(int v, int lo, int hi) {
    return v < lo ? lo : (v > hi ? hi : v);
}

// ---- weight prep: wfrag flat = (((t*2+ks)*4+fi)*64 + lane)*8 + j ----
// o = fi*16 + (lane&15), c = ks*32 + ((lane>>4)&3)*8 + j  (MFMA B-frag order)
__global__ void prep_weights(const float* __restrict__ weight,
                             unsigned short* __restrict__ wfrag) {
    int idx = blockIdx.x * 256 + threadIdx.x;
    if (idx >= 9 * 4096) return;
    int j  = idx & 7;
    int l  = (idx >> 3) & 63;
    int fi = (idx >> 9) & 3;
    int ks = (idx >> 11) & 1;
    int t  = idx >> 12;
    int o  = fi * 16 + (l & 15);
    int c  = ks * 32 + ((l >> 4) & 3) * 8 + j;
    wfrag[idx] = f2bf(weight[(o * C_ + c) * 9 + t]);
}

// ---- x transpose: xT[(b*128+h)*130 + (w+1)][c] = bf16(x[b][c][h][w]) ----
// cols 0 and 129 zeroed (w halo); row ZROW zeroed (h halo).
__global__ __launch_bounds__(256)
void prep_x(const float* __restrict__ x, unsigned short* __restrict__ xT) {
    __shared__ unsigned short tile[128][72];   // [w][c], 144B stride
    const int tid = threadIdx.x;
    const int blk = blockIdx.x;                // 1024 = 8 b x 128 h
    const int b = blk >> 7, h = blk & 127;
    const int w4 = tid & 31;                   // float4 slot along w
    const int cg = tid >> 5;                   // channel group 0..7

    float4 v[8];
    #pragma unroll
    for (int k = 0; k < 8; ++k) {
        int c = cg * 8 + k;
        v[k] = *(const float4*)&x[((b * C_ + c) * H_ + h) * W_ + w4 * 4];
    }
    #pragma unroll
    for (int j = 0; j < 4; ++j) {
        bf16x8 pk;
        #pragma unroll
        for (int k = 0; k < 8; ++k)
            pk[k] = (short)f2bf(((const float*)&v[k])[j]);
        *(bf16x8*)&tile[w4 * 4 + j][cg * 8] = pk;
    }
    __syncthreads();
    #pragma unroll
    for (int p = 0; p < 4; ++p) {
        int idx  = p * 256 + tid;
        int wrow = idx >> 3, ch = idx & 7;
        bf16x8 val = *(const bf16x8*)&tile[wrow][ch * 8];
        *(bf16x8*)&xT[(size_t)((b * H_ + h) * 130 + wrow + 1) * 64 + ch * 8] = val;
    }
    if (tid < 16) {                            // zero w-halo cols 0 and 129
        bf16x8 z = {};
        int col = (tid < 8) ? 0 : 129;
        int ch  = tid & 7;
        *(bf16x8*)&xT[(size_t)((b * H_ + h) * 130 + col) * 64 + ch * 8] = z;
    }
    if (blk == 0) {                            // zero h-halo row
        bf16x8 z = {};
        for (int i = tid; i < 1040; i += 256)
            *(bf16x8*)&xT[(size_t)ZROW * 64 + i * 8] = z;
    }
}

// ---- main: DMA-staged LDS from xT. Block = (b = blk&7, 2-row x 64-col tile).
// 4 waves: wave wv stages xs row wv; computes (hr = wv>>1, oh = wv&1):
// 1 output row x 64 px x 32 o.
// xs layout (r5-verified read path): byte(rc = r*66+col, c-chunk cb) =
//   rc*128 + ((cb*16) ^ swz(col)).  Staging achieves this with LINEAR LDS
//   dest + pre-swizzled SOURCE: chunk slot s of (r,col) loads c-block
//   s ^ key(col) from xT (same involution on both sides).
__global__ __launch_bounds__(256, 4)
void depthconv_dma(const float* __restrict__ depth,
                   const unsigned short* __restrict__ wfrag,
                   const unsigned short* __restrict__ xT,
                   const float* __restrict__ bias,
                   float* __restrict__ out) {
    __shared__ __align__(16) unsigned char xs[4 * 66 * 128];   // 33792 B
    __shared__ __align__(16) float sim[9][2][64];              // 4608 B
    __shared__ __align__(16) float dt[4][68];                  // 1088 B

    const int tid  = threadIdx.x;
    const int lane = tid & 63;
    const int wv   = tid >> 6;
    const int blk  = blockIdx.x;               // 1024
    const int b    = blk & 7;
    const int tile = blk >> 3;                 // 0..127
    const int h0   = (tile >> 1) * 2;
    const int w0   = (tile & 1) * 64;

    // ---- depth loads first (DMA issued after; in-order retire lets the
    //      dt writes wait only on these) ----
    int r0 = tid / 66, c0 = tid - r0 * 66;     // tid < 264 always
    int gh0 = h0 - 1 + r0, gw0 = w0 - 1 + c0;
    bool ok0 = ((unsigned)gh0 < (unsigned)H_) && ((unsigned)gw0 < (unsigned)W_);
    float dv0 = depth[(b * H_ + clampi(gh0, 0, H_ - 1)) * W_ + clampi(gw0, 0, W_ - 1)];
    float dv1 = 0.f;
    bool has1 = tid < 8, ok1 = false;
    int r1 = 3, c1 = 58 + tid;
    if (has1) {
        int gh = h0 - 1 + r1, gw = w0 - 1 + c1;
        ok1 = ((unsigned)gh < (unsigned)H_) && ((unsigned)gw < (unsigned)W_);
        dv1 = depth[(b * H_ + clampi(gh, 0, H_ - 1)) * W_ + clampi(gw, 0, W_ - 1)];
    }

    // ---- x staging: wave wv DMAs xs row wv (528 16B chunks; 8 full rounds
    //      + 1 overlapping idempotent round covering the 16-chunk tail) ----
    {
        int gh = h0 - 1 + wv;
        size_t rowbase = ((unsigned)gh < (unsigned)H_)
                       ? (size_t)((b * H_ + gh) * 130) : (size_t)ZROW;
        unsigned char* xsrow = xs + wv * (66 * 128);
        #pragma unroll
        for (int k = 0; k < 9; ++k) {
            const int cbase = (k < 8) ? k * 64 : 464;
            int ci  = cbase + lane;
            int col = ci >> 3, s = ci & 7;
            int key = (col ^ (col >> 3)) & 7;
            const unsigned short* src =
                xT + (rowbase + w0 + col) * 64 + (s ^ key) * 8;
            GLOAD_LDS16(src, xsrow + cbase * 16);
        }
    }

    // ---- dt writes + barrier ----
    dt[r0][c0] = ok0 ? dv0 : 0.f;
    if (has1) dt[r1][c1] = ok1 ? dv1 : 0.f;
    __syncthreads();

    // ---- sim[t][sr][px] ----
    for (int i = tid; i < 1152; i += 256) {
        int t = i >> 7, sr = (i >> 6) & 1, px = i & 63;
        int kh = t / 3, kw = t - kh * 3;
        sim[t][sr][px] = expf(-fabsf(dt[sr + kh][px + kw] - dt[sr + 1][px + 1]));
    }
    __syncthreads();      // sim visible + x DMA drained (vmcnt 0)

    // ---- main loop: barrier-free; wave = (row hr, o-half oh) ----
    const int hr = wv >> 1;
    const int oh = wv & 1;
    const int g  = lane >> 4;
    const int ln = lane & 15;

    float acc[4][2][4];                 // [pf][of][r]
    #pragma unroll
    for (int of = 0; of < 2; ++of) {
        float bv = bias[(oh * 2 + of) * 16 + ln];
        #pragma unroll
        for (int pf = 0; pf < 4; ++pf)
            #pragma unroll
            for (int r = 0; r < 4; ++r)
                acc[pf][of][r] = bv;
    }

    #pragma unroll 1
    for (int kh = 0; kh < 3; ++kh) {
        #pragma unroll
        for (int kw = 0; kw < 3; ++kw) {
            const int t = kh * 3 + kw;
            bf16x8 bfr[2][2];           // [ks][of]
            #pragma unroll
            for (int ks = 0; ks < 2; ++ks)
                #pragma unroll
                for (int of = 0; of < 2; ++of) {
                    int fi = oh * 2 + of;
                    bfr[ks][of] = *(const bf16x8*)(
                        wfrag + (((t * 2 + ks) * 4 + fi) * 64 + lane) * 8);
                }

            #pragma unroll
            for (int pf = 0; pf < 4; ++pf) {
                int col = pf * 16 + ln + kw;
                const unsigned char* rowp = xs + ((hr + kh) * 66 + col) * 128;
                bf16x8 af0 = *(const bf16x8*)(rowp + ((16 * g) ^ swz(col)));
                bf16x8 af1 = *(const bf16x8*)(rowp + ((64 + 16 * g) ^ swz(col)));

                f32x4 prt[2] = {};
                #pragma unroll
                for (int of = 0; of < 2; ++of)
                    prt[of] = __builtin_amdgcn_mfma_f32_16x16x32_bf16(
                        af0, bfr[0][of], prt[of], 0, 0, 0);
                #pragma unroll
                for (int of = 0; of < 2; ++of)
                    prt[of] = __builtin_amdgcn_mfma_f32_16x16x32_bf16(
                        af1, bfr[1][of], prt[of], 0, 0, 0);

                f32x4 sv = *(const f32x4*)&sim[t][hr][pf * 16 + g * 4];
                #pragma unroll
                for (int of = 0; of < 2; ++of)
                    #pragma unroll
                    for (int r = 0; r < 4; ++r)
                        acc[pf][of][r] = fmaf(sv[r], prt[of][r], acc[pf][of][r]);
            }
        }
    }

    // ---- direct stores (proven-clean pattern) ----
    const int h = h0 + hr;
    #pragma unroll
    for (int of = 0; of < 2; ++of) {
        int o = (oh * 2 + of) * 16 + ln;
        float* dst = out + (((size_t)(b * O_ + o) * H_ + h) * W_) + w0;
        #pragma unroll
        for (int pf = 0; pf < 4; ++pf) {
            f32x4 v = { acc[pf][of][0], acc[pf][of][1],
                        acc[pf][of][2], acc[pf][of][3] };
            *(f32x4*)(dst + pf * 16 + g * 4) = v;
        }
    }
}

// ================= fallback: round-5 kernel (36.6us), used if ws too small ==
__global__ __launch_bounds__(256, 2)
void depthconv_fb(const float* __restrict__ x,
                  const float* __restrict__ depth,
                  const unsigned short* __restrict__ wfrag,
                  const float* __restrict__ bias,
                  float* __restrict__ out) {
    __shared__ __align__(16) unsigned char xs[396 * 128];
    __shared__ __align__(16) float sim[9][4][64];
    __shared__ __align__(16) float dt[6][68];

    const int tid = threadIdx.x;
    const int blk = blockIdx.x;
    const int b   = blk >> 6;
    const int rem = blk & 63;
    const int h0  = (rem >> 1) * 4;
    const int w0  = (rem & 1) * 64;

    for (int i = tid; i < 396; i += 256) {
        int r = i / 66, col = i - r * 66;
        int gh = h0 - 1 + r, gw = w0 - 1 + col;
        bool ok = ((unsigned)gh < (unsigned)H_) && ((unsigned)gw < (unsigned)W_);
        float v = depth[(b * H_ + clampi(gh, 0, H_ - 1)) * W_ + clampi(gw, 0, W_ - 1)];
        dt[r][col] = ok ? v : 0.f;
    }
    __syncthreads();

    const int q  = tid & 15;
    const int pc = tid >> 4;
    float4 xa[12], xb[12];
    #pragma unroll
    for (int k = 0; k < 12; ++k) {
        int r = k >> 1, pair = pc + 16 * (k & 1);
        int ghc = clampi(h0 - 1 + r, 0, H_ - 1);
        const float* p = &x[((b * C_ + 2 * pair) * H_ + ghc) * W_ + w0 + q * 4];
        xa[k] = *(const float4*)p;
        xb[k] = *(const float4*)(p + HW_);
    }
    float hl0[2], hl1[2]; int hside[2], hpair[2], hr_[2]; bool hact[2];
    #pragma unroll
    for (int k = 0; k < 2; ++k) {
        int i = tid + 256 * k; hact[k] = false;
        if (i < 384) {
            int side = i & 1, pair = (i >> 1) & 31, r = i >> 6;
            hside[k] = side; hpair[k] = pair; hr_[k] = r; hact[k] = true;
            int gh = h0 - 1 + r, gw = side ? (w0 + 64) : (w0 - 1);
            bool ok = ((unsigned)gh < (unsigned)H_) && ((unsigned)gw < (unsigned)W_);
            const float* p = &x[((b * C_ + 2 * pair) * H_ + clampi(gh, 0, H_ - 1)) * W_
                                + clampi(gw, 0, W_ - 1)];
            float v0 = p[0], v1 = p[HW_];
            hl0[k] = ok ? v0 : 0.f; hl1[k] = ok ? v1 : 0.f;
        }
    }
    {
        int sr = (tid >> 6) & 3, px = tid & 63;
        float dc = dt[sr + 1][px + 1];
        #pragma unroll
        for (int t = 0; t < 9; ++t) {
            const int kh = t / 3, kw = t % 3;
            sim[t][sr][px] = expf(-fabsf(dt[sr + kh][px + kw] - dc));
        }
    }
    #pragma unroll
    for (int k = 0; k < 12; ++k) {
        int r = k >> 1, pair = pc + 16 * (k & 1);
        bool okh = (unsigned)(h0 - 1 + r) < (unsigned)H_;
        float va[4] = {xa[k].x, xa[k].y, xa[k].z, xa[k].w};
        float vb[4] = {xb[k].x, xb[k].y, xb[k].z, xb[k].w};
        #pragma unroll
        for (int m = 0; m < 4; ++m) {
            int col = 1 + q * 4 + m;
            float2 pr; pr.x = okh ? va[m] : 0.f; pr.y = okh ? vb[m] : 0.f;
            __hip_bfloat162 bv = __float22bfloat162_rn(pr);
            *(__hip_bfloat162*)(xs + (r * 66 + col) * 128 + ((4 * pair) ^ swz(col))) = bv;
        }
    }
    #pragma unroll
    for (int k = 0; k < 2; ++k) {
        if (hact[k]) {
            int col = hside[k] ? 65 : 0;
            float2 pr; pr.x = hl0[k]; pr.y = hl1[k];
            __hip_bfloat162 bv = __float22bfloat162_rn(pr);
            *(__hip_bfloat162*)(xs + (hr_[k] * 66 + col) * 128 + ((4 * hpair[k]) ^ swz(col))) = bv;
        }
    }
    __syncthreads();

    const int lane = tid & 63, hr = tid >> 6, g = lane >> 4, ln = lane & 15;
    float acc[4][4][4];
    #pragma unroll
    for (int of = 0; of < 4; ++of) {
        float bv = bias[of * 16 + ln];
        #pragma unroll
        for (int pf = 0; pf < 4; ++pf)
            #pragma unroll
            for (int r = 0; r < 4; ++r) acc[pf][of][r] = bv;
    }
    #pragma unroll 1
    for (int kh = 0; kh < 3; ++kh) {
        #pragma unroll
        for (int kw = 0; kw < 3; ++kw) {
            const int t = kh * 3 + kw;
            bf16x8 bfr[2][4];
            #pragma unroll
            for (int ks = 0; ks < 2; ++ks)
                #pragma unroll
                for (int of = 0; of < 4; ++of)
                    bfr[ks][of] = *(const bf16x8*)(
                        wfrag + (((t * 2 + ks) * 4 + of) * 64 + lane) * 8);
            #pragma unroll
            for (int pf = 0; pf < 4; ++pf) {
                int col = pf * 16 + ln + kw;
                const unsigned char* rowp = xs + ((hr + kh) * 66 + col) * 128;
                bf16x8 af0 = *(const bf16x8*)(rowp + ((16 * g) ^ swz(col)));
                bf16x8 af1 = *(const bf16x8*)(rowp + ((64 + 16 * g) ^ swz(col)));
                f32x4 prt[4] = {};
                #pragma unroll
                for (int of = 0; of < 4; ++of)
                    prt[of] = __builtin_amdgcn_mfma_f32_16x16x32_bf16(
                        af0, bfr[0][of], prt[of], 0, 0, 0);
                #pragma unroll
                for (int of = 0; of < 4; ++of)
                    prt[of] = __builtin_amdgcn_mfma_f32_16x16x32_bf16(
                        af1, bfr[1][of], prt[of], 0, 0, 0);
                f32x4 sv = *(const f32x4*)&sim[t][hr][pf * 16 + g * 4];
                #pragma unroll
                for (int of = 0; of < 4; ++of)
                    #pragma unroll
                    for (int r = 0; r < 4; ++r)
                        acc[pf][of][r] = fmaf(sv[r], prt[of][r], acc[pf][of][r]);
            }
        }
    }
    const int h = h0 + hr;
    #pragma unroll
    for (int of = 0; of < 4; ++of) {
        int o = of * 16 + ln;
        float* dst = out + (((size_t)(b * O_ + o) * H_ + h) * W_) + w0;
        #pragma unroll
        for (int pf = 0; pf < 4; ++pf) {
            f32x4 v = { acc[pf][of][0], acc[pf][of][1],
                        acc[pf][of][2], acc[pf][of][3] };
            *(f32x4*)(dst + pf * 16 + g * 4) = v;
        }
    }
}

extern "C" void kernel_launch(void* const* d_in, const int* in_sizes, int n_in,
                              void* d_out, int out_size, void* d_ws, size_t ws_size,
                              hipStream_t stream) {
    const float* x      = (const float*)d_in[0];
    const float* depth  = (const float*)d_in[1];
    const float* weight = (const float*)d_in[2];
    const float* bias   = (const float*)d_in[3];
    float* out          = (float*)d_out;
    unsigned short* wfrag = (unsigned short*)d_ws;

    prep_weights<<<dim3(144), dim3(256), 0, stream>>>(weight, wfrag);
    if (ws_size >= WS_NEEDED) {
        unsigned short* xT = wfrag + WFRAG_US;
        prep_x<<<dim3(1024), dim3(256), 0, stream>>>(x, xT);
        depthconv_dma<<<dim3(1024), dim3(256), 0, stream>>>(
            depth, wfrag, xT, bias, out);
    } else {
        depthconv_fb<<<dim3(512), dim3(256), 0, stream>>>(
            x, depth, wfrag, bias, out);
    }
}